// Round 2
// baseline (655.744 us; speedup 1.0000x reference)
//
#include <hip/hip_runtime.h>
#include <stdint.h>

#define NN 8192      // nodes
#define D0 128
#define D1 256
#define D2 256
#define QH 128
#define EPSV 1e-5f

using bf16x8 = __attribute__((ext_vector_type(8))) __bf16;
using f32x4  = __attribute__((ext_vector_type(4))) float;

__device__ __forceinline__ unsigned short f2bf(float f) {
    union { float f; unsigned int u; } v; v.f = f;
    unsigned int r = v.u + 0x7FFFu + ((v.u >> 16) & 1u);   // RNE
    return (unsigned short)(r >> 16);
}
__device__ __forceinline__ float bf2f(unsigned short h) {
    union { unsigned int u; float f; } v; v.u = ((unsigned int)h) << 16;
    return v.f;
}
// async global->LDS, 16B per lane; lds dest is wave-uniform base (HW: base + lane*16)
__device__ __forceinline__ void async_ld16(const void* g, void* l) {
    __builtin_amdgcn_global_load_lds(
        (__attribute__((address_space(1))) void*)(g),
        (__attribute__((address_space(3))) void*)(l), 16, 0, 0);
}

// ---------------- zero the small fp32 accumulators (colA,colB,colH1,s2 = 1024 floats) ----
__global__ void k_zero(float* __restrict__ p) {
    p[blockIdx.x * 256 + threadIdx.x] = 0.f;
}

// ---------------- K1: batchnorm partial stats ----------------
__global__ void k_stats(const float* __restrict__ state,
                        float* __restrict__ psum, float* __restrict__ psq) {
    int j = threadIdx.x;            // 0..127 = feature
    int b = blockIdx.x;             // 0..255, 32 rows each
    const float* p = state + (size_t)b * 32 * D0 + j;
    float s = 0.f, sq = 0.f;
#pragma unroll 4
    for (int r = 0; r < 32; ++r) { float x = p[(size_t)r * D0]; s += x; sq += x * x; }
    psum[b * D0 + j] = s;
    psq [b * D0 + j] = sq;
}

// ---------------- K1b: finalize scale/shift + c1 ----------------
__global__ void k_finalize(const float* __restrict__ psum, const float* __restrict__ psq,
                           const float* __restrict__ gamma, const float* __restrict__ beta,
                           const float* __restrict__ W1,
                           float* __restrict__ scale, float* __restrict__ shift,
                           float* __restrict__ c1) {
    __shared__ float s_shift[D0];
    int t = threadIdx.x;            // 256 threads
    if (t < D0) {
        float s = 0.f, sq = 0.f;
        for (int b = 0; b < 256; ++b) { s += psum[b * D0 + t]; sq += psq[b * D0 + t]; }
        float mean = s * (1.0f / NN);
        float var  = sq * (1.0f / NN) - mean * mean;
        float sc = gamma[t] * rsqrtf(var + EPSV);
        float sh = beta[t] - mean * sc;
        scale[t] = sc; shift[t] = sh; s_shift[t] = sh;
    }
    __syncthreads();
    // c1[n] = sum_k shift[k] * W1[k][n]
    float acc = 0.f;
    for (int k = 0; k < D0; ++k) acc += s_shift[k] * W1[(size_t)k * D1 + t];
    c1[t] = acc;
}

// ---------------- K0: weights -> bf16, transposed [n][k], W1 scaled ----------------
__global__ void k_prep_weights(const float* __restrict__ W1, const float* __restrict__ W2,
                               const float* __restrict__ scale,
                               unsigned short* __restrict__ W1st,  // [256][128]
                               unsigned short* __restrict__ W2t) { // [256][256]
    int idx = blockIdx.x * 256 + threadIdx.x;
    if (idx < 32768) {                       // W1st
        int n = idx >> 7, k = idx & 127;
        W1st[idx] = f2bf(W1[(size_t)k * D1 + n] * scale[k]);
    } else {                                 // W2t
        int i = idx - 32768; int n = i >> 8, k = i & 255;
        W2t[i] = f2bf(W2[(size_t)k * D2 + n]);
    }
}

// ---------------- small MFMA GEMM: out[m][n] = A[m][k] @ Bt[n][k]^T (+ bias) ----------------
// BM=32, BN=N, BK=32; 256 threads (4 waves), wave tile 32 x (N/4). grid.x = 8192/32 = 256
template <int N, int K, bool A_FP32, bool BIAS>
__global__ __launch_bounds__(256, 4) void k_small_gemm(
        const void* __restrict__ Aptr, const unsigned short* __restrict__ Bt,
        const float* __restrict__ bias, unsigned short* __restrict__ out) {
    constexpr int WN = N / 4;      // 64
    constexpr int NJ = WN / 16;    // 4
    constexpr int BI = N / 64;     // B-stage instrs per wave
    __shared__ unsigned short Alds[32 * 32];
    __shared__ unsigned short Blds[N * 32];
    int t = threadIdx.x, lane = t & 63, w = t >> 6;
    int m0 = blockIdx.x * 32;
    int lr = lane & 15, lk = (lane >> 4) * 8;
    int wc = w * WN;
    f32x4 acc[2][NJ] = {};

    for (int kk = 0; kk < K; kk += 32) {
        __syncthreads();
        if constexpr (A_FP32) {
            const float* A = (const float*)Aptr;
            int row = t >> 3, kc = (t & 7) * 4;
            float4 v = *(const float4*)(A + (size_t)(m0 + row) * K + kk + kc);
            uint2 p;
            p.x = ((unsigned)f2bf(v.y) << 16) | f2bf(v.x);
            p.y = ((unsigned)f2bf(v.w) << 16) | f2bf(v.z);
            *(uint2*)&Alds[row * 32 + kc] = p;
        } else {
            if (w < 2) {
                const unsigned short* A = (const unsigned short*)Aptr;
                int row = w * 16 + (lane >> 2);
                async_ld16(A + (size_t)(m0 + row) * K + kk + (lane & 3) * 8, &Alds[w * 512]);
            }
        }
#pragma unroll
        for (int i = 0; i < BI; ++i) {
            int n = w * WN + i * 16 + (lane >> 2);
            async_ld16(Bt + (size_t)n * K + kk + (lane & 3) * 8, &Blds[(w * WN + i * 16) * 32]);
        }
        __syncthreads();
        bf16x8 a[2], b[NJ];
#pragma unroll
        for (int i = 0; i < 2; ++i) a[i] = *(const bf16x8*)&Alds[(i * 16 + lr) * 32 + lk];
#pragma unroll
        for (int j = 0; j < NJ; ++j) b[j] = *(const bf16x8*)&Blds[(wc + j * 16 + lr) * 32 + lk];
#pragma unroll
        for (int i = 0; i < 2; ++i)
#pragma unroll
            for (int j = 0; j < NJ; ++j)
                acc[i][j] = __builtin_amdgcn_mfma_f32_16x16x32_bf16(a[i], b[j], acc[i][j], 0, 0, 0);
    }
    int q = lane >> 4;
#pragma unroll
    for (int j = 0; j < NJ; ++j) {
        int n = wc + j * 16 + lr;
        float bv = 0.f;
        if constexpr (BIAS) bv = bias[n];
#pragma unroll
        for (int i = 0; i < 2; ++i) {
#pragma unroll
            for (int r = 0; r < 4; ++r) {
                int m = m0 + i * 16 + q * 4 + r;
                out[(size_t)m * N + n] = f2bf(acc[i][j][r] + bv);
            }
        }
    }
}

// ---------------- transpose [8192][256] bf16 -> [256][8192] bf16, + fp32 colsum ----------------
__global__ void k_transpose(const unsigned short* __restrict__ in, unsigned short* __restrict__ out,
                            float* __restrict__ colsum) {
    __shared__ unsigned short tile[64 * 68];
    __shared__ float cp[4][64];
    int t = threadIdx.x;
    int r0 = blockIdx.x * 64, c0 = blockIdx.y * 64;
#pragma unroll
    for (int p = 0; p < 4; ++p) {
        int row = (t >> 4) + p * 16, col = (t & 15) * 4;
        *(ushort4*)&tile[row * 68 + col] = *(const ushort4*)&in[(size_t)(r0 + row) * 256 + c0 + col];
    }
    __syncthreads();
    int n = t >> 2;
#pragma unroll
    for (int s = 0; s < 2; ++s) {
        int mo = (t & 3) * 16 + s * 8;
        unsigned short v[8];
#pragma unroll
        for (int e = 0; e < 8; ++e) v[e] = tile[(mo + e) * 68 + n];
        *(uint4*)&out[(size_t)(c0 + n) * NN + r0 + mo] = *(const uint4*)v;
    }
    // column sums (fp32) of the bf16 tile -> global atomic
    int col = t & 63, gg = t >> 6;
    float s = 0.f;
#pragma unroll
    for (int r = 0; r < 16; ++r) s += bf2f(tile[(gg * 16 + r) * 68 + col]);
    cp[gg][col] = s;
    __syncthreads();
    if (t < 64) atomicAdd(colsum + c0 + t, cp[0][t] + cp[1][t] + cp[2][t] + cp[3][t]);
}

// ---------------- big GEMM: Cp[sk][m][n] partial of A[8192x8192 fp32] @ Yt^T, + A rowsums ----
// BM=128, BN=256, BK=32, split-K=4 (chunks of 2048). 512 threads = 8 waves of 64x64.
__global__ __launch_bounds__(512, 2) void k_big_gemm(
        const float* __restrict__ A, const unsigned short* __restrict__ Yt,
        float* __restrict__ Cp, float* __restrict__ rsPart) {
    __shared__ unsigned short Alds[128 * 32];   // [m][k] bf16
    __shared__ unsigned short Blds[256 * 32];   // [n][k] bf16
    int t = threadIdx.x, lane = t & 63, w = t >> 6;
    int m0 = blockIdx.x * 128;
    int kbeg = blockIdx.y * 2048;
    int wr = (w & 1) * 64, wc = (w >> 1) * 64;
    int lr = lane & 15, lk = (lane >> 4) * 8;
    f32x4 acc[4][4] = {};

    int arow = t >> 3;                 // 0..63
    int akc = (t & 7) * 4;
    const float* ag = A + (size_t)(m0 + arow) * NN + kbeg + akc;
    int bn = w * 32 + (lane >> 2);
    const unsigned short* bg = Yt + (size_t)bn * NN + kbeg + (lane & 3) * 8;
    float rs0 = 0.f, rs1 = 0.f;        // fp32 rowsum partials (pre-quantization)

    for (int kk = 0; kk < 2048; kk += 32) {
        __syncthreads();
        {   // A: fp32 -> bf16 through VGPRs, 2 rows per thread (arow, arow+64)
            float4 v0 = *(const float4*)(ag + kk);
            float4 v1 = *(const float4*)(ag + (size_t)64 * NN + kk);
            rs0 += v0.x + v0.y + v0.z + v0.w;
            rs1 += v1.x + v1.y + v1.z + v1.w;
            uint2 p0, p1;
            p0.x = ((unsigned)f2bf(v0.y) << 16) | f2bf(v0.x);
            p0.y = ((unsigned)f2bf(v0.w) << 16) | f2bf(v0.z);
            p1.x = ((unsigned)f2bf(v1.y) << 16) | f2bf(v1.x);
            p1.y = ((unsigned)f2bf(v1.w) << 16) | f2bf(v1.z);
            *(uint2*)&Alds[arow * 32 + akc] = p0;
            *(uint2*)&Alds[(arow + 64) * 32 + akc] = p1;
        }
        // B: async 16B/lane, 2 instrs per wave (16 n-rows each)
        async_ld16(bg + kk, &Blds[(w * 32) * 32]);
        async_ld16(bg + (size_t)16 * NN + kk, &Blds[(w * 32 + 16) * 32]);
        __syncthreads();
        bf16x8 a[4], b[4];
#pragma unroll
        for (int i = 0; i < 4; ++i) a[i] = *(const bf16x8*)&Alds[(wr + i * 16 + lr) * 32 + lk];
#pragma unroll
        for (int j = 0; j < 4; ++j) b[j] = *(const bf16x8*)&Blds[(wc + j * 16 + lr) * 32 + lk];
#pragma unroll
        for (int i = 0; i < 4; ++i)
#pragma unroll
            for (int j = 0; j < 4; ++j)
                acc[i][j] = __builtin_amdgcn_mfma_f32_16x16x32_bf16(a[i], b[j], acc[i][j], 0, 0, 0);
    }
    // reduce rowsums across the 8 lanes sharing one row (lanes differing in bits 0..2)
#pragma unroll
    for (int m = 1; m < 8; m <<= 1) {
        rs0 += __shfl_xor(rs0, m, 64);
        rs1 += __shfl_xor(rs1, m, 64);
    }
    if ((lane & 7) == 0) {
        rsPart[(size_t)blockIdx.y * NN + m0 + arow] = rs0;
        rsPart[(size_t)blockIdx.y * NN + m0 + arow + 64] = rs1;
    }
    float* outp = Cp + (size_t)blockIdx.y * NN * 256;
    int q = lane >> 4;
#pragma unroll
    for (int i = 0; i < 4; ++i)
#pragma unroll
        for (int j = 0; j < 4; ++j) {
            int n = wc + j * 16 + lr;
#pragma unroll
            for (int r = 0; r < 4; ++r) {
                int m = m0 + wr + i * 16 + q * 4 + r;
                outp[(size_t)m * 256 + n] = acc[i][j][r];
            }
        }
}

// ---------------- s2[n] = colB[n] - sum_k colH1[k]*W2[k][n] ----------------
__global__ void k_s2(const float* __restrict__ colB, const float* __restrict__ colH1,
                     const float* __restrict__ W2, float* __restrict__ s2) {
    int n = threadIdx.x;
    float acc = 0.f;
    for (int k = 0; k < 256; ++k) acc += colH1[k] * W2[(size_t)k * 256 + n];
    s2[n] = colB[n] - acc;
}

// ---------------- reduce split-K + bias + colsum-correction + relu ----------------
// 256 blocks x 256 threads; block handles 32 rows x 256 cols.
// out = relu(sum_s Cp[s] + bias[n] - rs[m]*sn[n]/8192); STORE_BF16 also accumulates colsum(out).
template <bool STORE_BF16>
__global__ __launch_bounds__(256) void k_reduce(
        const float* __restrict__ Cp, const float* __restrict__ rsPart,
        const float* __restrict__ bias, const float* __restrict__ sn,
        void* __restrict__ outv, float* __restrict__ colH1) {
    __shared__ float rs_s[32];
    __shared__ float cs[4][256];
    int t = threadIdx.x;
    int m0 = blockIdx.x * 32;
    const size_t S = (size_t)NN * 256;
    if (t < 32) {
        float r = 0.f;
        for (int s = 0; s < 4; ++s) r += rsPart[(size_t)s * NN + m0 + t];
        rs_s[t] = r * (1.0f / 8192.0f);
    }
    __syncthreads();
    int g = t >> 6, cq = (t & 63) * 4;
    float4 snv = *(const float4*)(sn + cq);
    float4 bv  = *(const float4*)(bias + cq);
    float c0 = 0.f, c1a = 0.f, c2 = 0.f, c3 = 0.f;
#pragma unroll
    for (int r8 = 0; r8 < 8; ++r8) {
        int row = m0 + g * 8 + r8;
        size_t base = (size_t)row * 256 + cq;
        float4 a0 = *(const float4*)(Cp + base);
        float4 a1 = *(const float4*)(Cp + S + base);
        float4 a2 = *(const float4*)(Cp + 2 * S + base);
        float4 a3 = *(const float4*)(Cp + 3 * S + base);
        float rsv = rs_s[g * 8 + r8];
        float x0 = fmaxf(a0.x + a1.x + a2.x + a3.x + bv.x - rsv * snv.x, 0.f);
        float x1 = fmaxf(a0.y + a1.y + a2.y + a3.y + bv.y - rsv * snv.y, 0.f);
        float x2 = fmaxf(a0.z + a1.z + a2.z + a3.z + bv.z - rsv * snv.z, 0.f);
        float x3 = fmaxf(a0.w + a1.w + a2.w + a3.w + bv.w - rsv * snv.w, 0.f);
        if constexpr (STORE_BF16) {
            ushort4 o; o.x = f2bf(x0); o.y = f2bf(x1); o.z = f2bf(x2); o.w = f2bf(x3);
            *(ushort4*)((unsigned short*)outv + base) = o;
            c0 += x0; c1a += x1; c2 += x2; c3 += x3;
        } else {
            float4 o; o.x = x0; o.y = x1; o.z = x2; o.w = x3;
            *(float4*)((float*)outv + base) = o;
        }
    }
    if constexpr (STORE_BF16) {
        cs[g][cq] = c0; cs[g][cq + 1] = c1a; cs[g][cq + 2] = c2; cs[g][cq + 3] = c3;
        __syncthreads();
        float tot = cs[0][t] + cs[1][t] + cs[2][t] + cs[3][t];
        atomicAdd(colH1 + t, tot);
    }
}

// ---------------- fp32 Q-head: out[m] = relu(H2[m]@Wq1 + bq1) @ Wq2 + bq2 ----------------
// 1024 blocks x 128 threads; block handles 8 rows.
__global__ __launch_bounds__(128) void k_qhead(
        const float* __restrict__ H2, const float* __restrict__ Wq1,
        const float* __restrict__ bq1, const float* __restrict__ Wq2,
        const float* __restrict__ bq2, float* __restrict__ out) {
    __shared__ float sh[8][256];
    __shared__ float red[2][8];
    int t = threadIdx.x;
    int m0 = blockIdx.x * 8;
#pragma unroll
    for (int i = 0; i < 4; ++i) {
        int idx = i * 512 + t * 4;          // 0..2047
        int row = idx >> 8, col = idx & 255;
        *(float4*)&sh[row][col] = *(const float4*)(H2 + (size_t)(m0 + row) * 256 + col);
    }
    __syncthreads();
    float acc[8];
    float bq = bq1[t];
#pragma unroll
    for (int r = 0; r < 8; ++r) acc[r] = bq;
    for (int n = 0; n < 256; ++n) {
        float wv = Wq1[(size_t)n * QH + t];
#pragma unroll
        for (int r = 0; r < 8; ++r) acc[r] = fmaf(sh[r][n], wv, acc[r]);
    }
    float wq2 = Wq2[t];
    float bq2v = bq2[0];
    int lane = t & 63, wv2 = t >> 6;
#pragma unroll
    for (int r = 0; r < 8; ++r) {
        float v = fmaxf(acc[r], 0.f) * wq2;
#pragma unroll
        for (int d = 32; d > 0; d >>= 1) v += __shfl_down(v, d, 64);
        if (lane == 0) red[wv2][r] = v;
    }
    __syncthreads();
    if (t < 8) out[m0 + t] = red[0][t] + red[1][t] + bq2v;
}

extern "C" void kernel_launch(void* const* d_in, const int* in_sizes, int n_in,
                              void* d_out, int out_size, void* d_ws, size_t ws_size,
                              hipStream_t stream) {
    const float* state = (const float*)d_in[0];
    const float* adj   = (const float*)d_in[1];
    const float* gamma = (const float*)d_in[2];
    const float* beta  = (const float*)d_in[3];
    const float* W1    = (const float*)d_in[4];
    const float* b1    = (const float*)d_in[5];
    const float* W2    = (const float*)d_in[6];
    const float* b2    = (const float*)d_in[7];
    const float* Wq1   = (const float*)d_in[8];
    const float* bq1   = (const float*)d_in[9];
    const float* Wq2   = (const float*)d_in[10];
    const float* bq2   = (const float*)d_in[11];
    float* out = (float*)d_out;

    char* ws = (char*)d_ws;
    float* psum  = (float*)(ws + 0);         // 128KB
    float* psq   = (float*)(ws + 131072);    // 128KB
    float* scale = (float*)(ws + 262144);
    float* shift = (float*)(ws + 262656);
    float* c1    = (float*)(ws + 263168);
    float* colA  = (float*)(ws + 264192);    // colsum(Y1q), 1KB
    float* colB  = (float*)(ws + 265216);    // colsum(Y2q), 1KB
    float* colH1 = (float*)(ws + 266240);    // colsum(H1 fp32), 1KB
    float* s2    = (float*)(ws + 267264);    // 1KB
    unsigned short* W1st = (unsigned short*)(ws + 268288);   // [256][128] bf16
    unsigned short* W2t  = (unsigned short*)(ws + 333824);   // [256][256] bf16
    unsigned short* Ybuf = (unsigned short*)(ws + (size_t)1  * (1u << 20)); // [8192][256] bf16
    unsigned short* Ytb  = (unsigned short*)(ws + (size_t)5  * (1u << 20)); // [256][8192] bf16
    unsigned short* Hbuf = (unsigned short*)(ws + (size_t)9  * (1u << 20)); // [8192][256] bf16
    float*          H2f  = (float*)(ws + (size_t)13 * (1u << 20));          // [8192][256] fp32
    float*          rsP  = (float*)(ws + (size_t)21 * (1u << 20));          // [4][8192] fp32
    float*          Cp   = (float*)(ws + (size_t)22 * (1u << 20));          // [4][8192][256] fp32

    k_zero<<<4, 256, 0, stream>>>(colA);     // colA..s2 contiguous 4KB
    k_stats<<<256, 128, 0, stream>>>(state, psum, psq);
    k_finalize<<<1, 256, 0, stream>>>(psum, psq, gamma, beta, W1, scale, shift, c1);
    k_prep_weights<<<384, 256, 0, stream>>>(W1, W2, scale, W1st, W2t);

    // Y1 = bn(state) @ W1  (= state @ (scale*W1) + c1); colsum(Y1_true) == 0 exactly
    k_small_gemm<256, 128, true, true><<<256, 256, 0, stream>>>(state, W1st, c1, Ybuf);
    k_transpose<<<dim3(128, 4), 256, 0, stream>>>(Ybuf, Ytb, colA);
    k_big_gemm<<<dim3(64, 4), 512, 0, stream>>>(adj, Ytb, Cp, rsP);
    k_reduce<true><<<256, 256, 0, stream>>>(Cp, rsP, b1, colA, Hbuf, colH1);   // H1 bf16 + colsum

    // Y2 = H1 @ W2; colsum(Y2_true) = colH1 @ W2 (fp32)
    k_small_gemm<256, 256, false, false><<<256, 256, 0, stream>>>(Hbuf, W2t, nullptr, Ybuf);
    k_transpose<<<dim3(128, 4), 256, 0, stream>>>(Ybuf, Ytb, colB);
    k_s2<<<1, 256, 0, stream>>>(colB, colH1, W2, s2);
    k_big_gemm<<<dim3(64, 4), 512, 0, stream>>>(adj, Ytb, Cp, rsP);
    k_reduce<false><<<256, 256, 0, stream>>>(Cp, rsP, b2, s2, H2f, nullptr);   // H2 fp32

    // q = relu(H2 @ Wq1 + bq1) @ Wq2 + bq2  (all fp32)
    k_qhead<<<1024, 128, 0, stream>>>(H2f, Wq1, bq1, Wq2, bq2, out);
}

// Round 3
// 608.060 us; speedup vs baseline: 1.0784x; 1.0784x over previous
//
#include <hip/hip_runtime.h>
#include <stdint.h>

#define NN 8192      // nodes
#define D0 128
#define D1 256
#define D2 256
#define QH 128
#define EPSV 1e-5f

using bf16x8 = __attribute__((ext_vector_type(8))) __bf16;
using f32x4  = __attribute__((ext_vector_type(4))) float;

__device__ __forceinline__ unsigned short f2bf(float f) {
    union { float f; unsigned int u; } v; v.f = f;
    unsigned int r = v.u + 0x7FFFu + ((v.u >> 16) & 1u);   // RNE
    return (unsigned short)(r >> 16);
}
__device__ __forceinline__ float bf2f(unsigned short h) {
    union { unsigned int u; float f; } v; v.u = ((unsigned int)h) << 16;
    return v.f;
}
// async global->LDS, 16B per lane; lds dest is wave-uniform base (HW: base + lane*16)
__device__ __forceinline__ void async_ld16(const void* g, void* l) {
    __builtin_amdgcn_global_load_lds(
        (__attribute__((address_space(1))) void*)(g),
        (__attribute__((address_space(3))) void*)(l), 16, 0, 0);
}

// ---------------- cast A fp32 -> bf16 (row-major) + fp32 rowsums ----------------
// one block per row; 256 threads x 32 elements
__global__ __launch_bounds__(256) void k_castA(const float* __restrict__ A,
                                               unsigned short* __restrict__ Abf,
                                               float* __restrict__ rs) {
    __shared__ float sred[256];
    int t = threadIdx.x;
    size_t row = blockIdx.x;
    const float* ap = A + row * NN;
    unsigned short* op = Abf + row * NN;
    float s = 0.f;
#pragma unroll
    for (int i = 0; i < 8; ++i) {
        int c = i * 1024 + t * 4;
        float4 v = *(const float4*)(ap + c);
        s += v.x + v.y + v.z + v.w;
        ushort4 o; o.x = f2bf(v.x); o.y = f2bf(v.y); o.z = f2bf(v.z); o.w = f2bf(v.w);
        *(ushort4*)(op + c) = o;
    }
    sred[t] = s;
    __syncthreads();
    if (t < 128) sred[t] += sred[t + 128];
    __syncthreads();
    if (t < 64) {
        float v = sred[t] + sred[t + 64];
#pragma unroll
        for (int d = 32; d > 0; d >>= 1) v += __shfl_down(v, d, 64);
        if (t == 0) rs[row] = v;
    }
}

// ---------------- zero the small fp32 accumulators (colA,colB,colH1,s2) ----------
__global__ void k_zero(float* __restrict__ p) {
    p[blockIdx.x * 256 + threadIdx.x] = 0.f;
}

// ---------------- batchnorm partial stats ----------------
__global__ void k_stats(const float* __restrict__ state,
                        float* __restrict__ psum, float* __restrict__ psq) {
    int j = threadIdx.x;            // 0..127 = feature
    int b = blockIdx.x;             // 0..255, 32 rows each
    const float* p = state + (size_t)b * 32 * D0 + j;
    float s = 0.f, sq = 0.f;
#pragma unroll 4
    for (int r = 0; r < 32; ++r) { float x = p[(size_t)r * D0]; s += x; sq += x * x; }
    psum[b * D0 + j] = s;
    psq [b * D0 + j] = sq;
}

// ---------------- finalize scale/shift + c1 ----------------
__global__ void k_finalize(const float* __restrict__ psum, const float* __restrict__ psq,
                           const float* __restrict__ gamma, const float* __restrict__ beta,
                           const float* __restrict__ W1,
                           float* __restrict__ scale, float* __restrict__ shift,
                           float* __restrict__ c1) {
    __shared__ float s_shift[D0];
    int t = threadIdx.x;            // 256 threads
    if (t < D0) {
        float s = 0.f, sq = 0.f;
        for (int b = 0; b < 256; ++b) { s += psum[b * D0 + t]; sq += psq[b * D0 + t]; }
        float mean = s * (1.0f / NN);
        float var  = sq * (1.0f / NN) - mean * mean;
        float sc = gamma[t] * rsqrtf(var + EPSV);
        float sh = beta[t] - mean * sc;
        scale[t] = sc; shift[t] = sh; s_shift[t] = sh;
    }
    __syncthreads();
    float acc = 0.f;
    for (int k = 0; k < D0; ++k) acc += s_shift[k] * W1[(size_t)k * D1 + t];
    c1[t] = acc;
}

// ---------------- weights -> bf16, transposed [n][k], W1 scaled ----------------
__global__ void k_prep_weights(const float* __restrict__ W1, const float* __restrict__ W2,
                               const float* __restrict__ scale,
                               unsigned short* __restrict__ W1st,  // [256][128]
                               unsigned short* __restrict__ W2t) { // [256][256]
    int idx = blockIdx.x * 256 + threadIdx.x;
    if (idx < 32768) {
        int n = idx >> 7, k = idx & 127;
        W1st[idx] = f2bf(W1[(size_t)k * D1 + n] * scale[k]);
    } else {
        int i = idx - 32768; int n = i >> 8, k = i & 255;
        W2t[i] = f2bf(W2[(size_t)k * D2 + n]);
    }
}

// ---------------- small MFMA GEMM: out[m][n] = A[m][k] @ Bt[n][k]^T (+ bias) ----------------
template <int N, int K, bool A_FP32, bool BIAS>
__global__ __launch_bounds__(256, 4) void k_small_gemm(
        const void* __restrict__ Aptr, const unsigned short* __restrict__ Bt,
        const float* __restrict__ bias, unsigned short* __restrict__ out) {
    constexpr int WN = N / 4;
    constexpr int NJ = WN / 16;
    constexpr int BI = N / 64;
    __shared__ unsigned short Alds[32 * 32];
    __shared__ unsigned short Blds[N * 32];
    int t = threadIdx.x, lane = t & 63, w = t >> 6;
    int m0 = blockIdx.x * 32;
    int lr = lane & 15, lk = (lane >> 4) * 8;
    int wc = w * WN;
    f32x4 acc[2][NJ] = {};

    for (int kk = 0; kk < K; kk += 32) {
        __syncthreads();
        if constexpr (A_FP32) {
            const float* A = (const float*)Aptr;
            int row = t >> 3, kc = (t & 7) * 4;
            float4 v = *(const float4*)(A + (size_t)(m0 + row) * K + kk + kc);
            uint2 p;
            p.x = ((unsigned)f2bf(v.y) << 16) | f2bf(v.x);
            p.y = ((unsigned)f2bf(v.w) << 16) | f2bf(v.z);
            *(uint2*)&Alds[row * 32 + kc] = p;
        } else {
            if (w < 2) {
                const unsigned short* A = (const unsigned short*)Aptr;
                int row = w * 16 + (lane >> 2);
                async_ld16(A + (size_t)(m0 + row) * K + kk + (lane & 3) * 8, &Alds[w * 512]);
            }
        }
#pragma unroll
        for (int i = 0; i < BI; ++i) {
            int n = w * WN + i * 16 + (lane >> 2);
            async_ld16(Bt + (size_t)n * K + kk + (lane & 3) * 8, &Blds[(w * WN + i * 16) * 32]);
        }
        __syncthreads();
        bf16x8 a[2], b[NJ];
#pragma unroll
        for (int i = 0; i < 2; ++i) a[i] = *(const bf16x8*)&Alds[(i * 16 + lr) * 32 + lk];
#pragma unroll
        for (int j = 0; j < NJ; ++j) b[j] = *(const bf16x8*)&Blds[(wc + j * 16 + lr) * 32 + lk];
#pragma unroll
        for (int i = 0; i < 2; ++i)
#pragma unroll
            for (int j = 0; j < NJ; ++j)
                acc[i][j] = __builtin_amdgcn_mfma_f32_16x16x32_bf16(a[i], b[j], acc[i][j], 0, 0, 0);
    }
    int q = lane >> 4;
#pragma unroll
    for (int j = 0; j < NJ; ++j) {
        int n = wc + j * 16 + lr;
        float bv = 0.f;
        if constexpr (BIAS) bv = bias[n];
#pragma unroll
        for (int i = 0; i < 2; ++i) {
#pragma unroll
            for (int r = 0; r < 4; ++r) {
                int m = m0 + i * 16 + q * 4 + r;
                out[(size_t)m * N + n] = f2bf(acc[i][j][r] + bv);
            }
        }
    }
}

// ---------------- transpose [8192][256] bf16 -> [256][8192] bf16, + fp32 colsum ----------------
__global__ void k_transpose(const unsigned short* __restrict__ in, unsigned short* __restrict__ out,
                            float* __restrict__ colsum) {
    __shared__ unsigned short tile[64 * 68];
    __shared__ float cp[4][64];
    int t = threadIdx.x;
    int r0 = blockIdx.x * 64, c0 = blockIdx.y * 64;
#pragma unroll
    for (int p = 0; p < 4; ++p) {
        int row = (t >> 4) + p * 16, col = (t & 15) * 4;
        *(ushort4*)&tile[row * 68 + col] = *(const ushort4*)&in[(size_t)(r0 + row) * 256 + c0 + col];
    }
    __syncthreads();
    int n = t >> 2;
#pragma unroll
    for (int s = 0; s < 2; ++s) {
        int mo = (t & 3) * 16 + s * 8;
        unsigned short v[8];
#pragma unroll
        for (int e = 0; e < 8; ++e) v[e] = tile[(mo + e) * 68 + n];
        *(uint4*)&out[(size_t)(c0 + n) * NN + r0 + mo] = *(const uint4*)v;
    }
    int col = t & 63, gg = t >> 6;
    float s = 0.f;
#pragma unroll
    for (int r = 0; r < 16; ++r) s += bf2f(tile[(gg * 16 + r) * 68 + col]);
    cp[gg][col] = s;
    __syncthreads();
    if (t < 64) atomicAdd(colsum + c0 + t, cp[0][t] + cp[1][t] + cp[2][t] + cp[3][t]);
}

// ---------------- big GEMM: pure-async m97 structure, XOR-swizzled LDS ----------------
// C[m,n] partial = Abf[8192x8192 bf16] @ Yt[n][k]^T over k-chunk of 1024.
// BM=128, BN=256, BK=32, split-K=8. grid(64,8), 512 threads = 8 waves of 64x64.
// LDS chunk layout: 16B chunk (row,h) stored at chunk index row*4 + (h ^ xs(row)),
// xs(r) = (r ^ (r>>2)) & 3  -> ds_read_b128 bank-quads all distinct across 8 rows.
__global__ __launch_bounds__(512, 4) void k_big_gemm2(
        const unsigned short* __restrict__ Abf, const unsigned short* __restrict__ Yt,
        float* __restrict__ Cp) {
    __shared__ unsigned short Alds[128 * 32];   // 8KB
    __shared__ unsigned short Blds[256 * 32];   // 16KB
    int t = threadIdx.x, lane = t & 63, w = t >> 6;
    int m0 = blockIdx.x * 128;
    int kbeg = blockIdx.y * 1024;
    int wr = (w & 1) * 64, wc = (w >> 1) * 64;
    int lr = lane & 15, q = lane >> 4;
    f32x4 acc[4][4] = {};

    // staging addresses (swizzled k-chunk per lane)
    int srow = lane >> 2;                              // 0..15 within 16-row group
    int hsw = (lane & 3) ^ ((srow ^ (srow >> 2)) & 3); // k-chunk 0..3 this lane fetches
    const unsigned short* agp = Abf + (size_t)(m0 + w * 16 + srow) * NN + kbeg + hsw * 8;
    const unsigned short* bg0 = Yt + (size_t)(w * 32 + srow) * NN + kbeg + hsw * 8;
    const unsigned short* bg1 = Yt + (size_t)(w * 32 + 16 + srow) * NN + kbeg + hsw * 8;
    unsigned short* aLb = Alds + w * 512;   // wave-uniform LDS bases
    unsigned short* bLb0 = Blds + w * 1024;
    unsigned short* bLb1 = Blds + w * 1024 + 512;
    // read-side swizzle offset (shorts)
    int xsr = (lr ^ (lr >> 2)) & 3;
    int lks = ((q ^ xsr) & 3) * 8;

    for (int kk = 0; kk < 1024; kk += 32) {
        __syncthreads();
        async_ld16(agp + kk, aLb);
        async_ld16(bg0 + kk, bLb0);
        async_ld16(bg1 + kk, bLb1);
        __syncthreads();
        bf16x8 a[4], b[4];
#pragma unroll
        for (int i = 0; i < 4; ++i) a[i] = *(const bf16x8*)&Alds[(wr + i * 16 + lr) * 32 + lks];
#pragma unroll
        for (int j = 0; j < 4; ++j) b[j] = *(const bf16x8*)&Blds[(wc + j * 16 + lr) * 32 + lks];
#pragma unroll
        for (int i = 0; i < 4; ++i)
#pragma unroll
            for (int j = 0; j < 4; ++j)
                acc[i][j] = __builtin_amdgcn_mfma_f32_16x16x32_bf16(a[i], b[j], acc[i][j], 0, 0, 0);
    }
    float* outp = Cp + (size_t)blockIdx.y * NN * 256;
#pragma unroll
    for (int i = 0; i < 4; ++i)
#pragma unroll
        for (int j = 0; j < 4; ++j) {
            int n = wc + j * 16 + lr;
#pragma unroll
            for (int r = 0; r < 4; ++r) {
                int m = m0 + wr + i * 16 + q * 4 + r;
                outp[(size_t)m * 256 + n] = acc[i][j][r];
            }
        }
}

// ---------------- s2[n] = colB[n] - sum_k colH1[k]*W2[k][n] ----------------
__global__ void k_s2(const float* __restrict__ colB, const float* __restrict__ colH1,
                     const float* __restrict__ W2, float* __restrict__ s2) {
    int n = threadIdx.x;
    float acc = 0.f;
    for (int k = 0; k < 256; ++k) acc += colH1[k] * W2[(size_t)k * 256 + n];
    s2[n] = colB[n] - acc;
}

// ---------------- reduce 8 split-K partials + bias + colsum-corr + relu -> bf16 H1 ----------
// 512 blocks x 256 threads; block = 16 rows x 256 cols. Also accumulates colsum(H1).
__global__ __launch_bounds__(256) void k_reduce8(
        const float* __restrict__ Cp, const float* __restrict__ rsA,
        const float* __restrict__ bias, const float* __restrict__ sn,
        unsigned short* __restrict__ out, float* __restrict__ colH1) {
    __shared__ float rs_s[16];
    __shared__ float cs[4][256];
    int t = threadIdx.x;
    int m0 = blockIdx.x * 16;
    const size_t S = (size_t)NN * 256;
    if (t < 16) rs_s[t] = rsA[m0 + t] * (1.0f / 8192.0f);
    __syncthreads();
    int g = t >> 6, cq = (t & 63) * 4;
    float4 snv = *(const float4*)(sn + cq);
    float4 bv  = *(const float4*)(bias + cq);
    float c0 = 0.f, c1a = 0.f, c2 = 0.f, c3 = 0.f;
#pragma unroll
    for (int r4 = 0; r4 < 4; ++r4) {
        int row = g * 4 + r4;
        size_t base = (size_t)(m0 + row) * 256 + cq;
        float4 a = {0.f, 0.f, 0.f, 0.f};
#pragma unroll
        for (int s = 0; s < 8; ++s) {
            float4 p = *(const float4*)(Cp + (size_t)s * S + base);
            a.x += p.x; a.y += p.y; a.z += p.z; a.w += p.w;
        }
        float rsv = rs_s[row];
        float x0 = fmaxf(a.x + bv.x - rsv * snv.x, 0.f);
        float x1 = fmaxf(a.y + bv.y - rsv * snv.y, 0.f);
        float x2 = fmaxf(a.z + bv.z - rsv * snv.z, 0.f);
        float x3 = fmaxf(a.w + bv.w - rsv * snv.w, 0.f);
        ushort4 o; o.x = f2bf(x0); o.y = f2bf(x1); o.z = f2bf(x2); o.w = f2bf(x3);
        *(ushort4*)(out + base) = o;
        c0 += x0; c1a += x1; c2 += x2; c3 += x3;
    }
    cs[g][cq] = c0; cs[g][cq + 1] = c1a; cs[g][cq + 2] = c2; cs[g][cq + 3] = c3;
    __syncthreads();
    float tot = cs[0][t] + cs[1][t] + cs[2][t] + cs[3][t];
    atomicAdd(colH1 + t, tot);
}

// ---------------- fused: reduce 8 partials -> H2(fp32, LDS only) -> Q-head -> out -------
// 512 blocks x 256 threads; block = 16 rows. q = relu(H2@Wq1+bq1)@Wq2 + bq2
__global__ __launch_bounds__(256) void k_reduce_qhead(
        const float* __restrict__ Cp, const float* __restrict__ rsA,
        const float* __restrict__ bias, const float* __restrict__ sn,
        const float* __restrict__ Wq1, const float* __restrict__ bq1,
        const float* __restrict__ Wq2, const float* __restrict__ bq2,
        float* __restrict__ out) {
    __shared__ float sh[16][256];   // 16KB
    __shared__ float rs_s[16];
    __shared__ float red[4][8];
    int t = threadIdx.x;
    int m0 = blockIdx.x * 16;
    const size_t S = (size_t)NN * 256;
    if (t < 16) rs_s[t] = rsA[m0 + t] * (1.0f / 8192.0f);
    __syncthreads();
    int g = t >> 6, cq = (t & 63) * 4;
    float4 snv = *(const float4*)(sn + cq);
    float4 bv  = *(const float4*)(bias + cq);
#pragma unroll
    for (int r4 = 0; r4 < 4; ++r4) {
        int row = g * 4 + r4;
        size_t base = (size_t)(m0 + row) * 256 + cq;
        float4 a = {0.f, 0.f, 0.f, 0.f};
#pragma unroll
        for (int s = 0; s < 8; ++s) {
            float4 p = *(const float4*)(Cp + (size_t)s * S + base);
            a.x += p.x; a.y += p.y; a.z += p.z; a.w += p.w;
        }
        float rsv = rs_s[row];
        float4 o;
        o.x = fmaxf(a.x + bv.x - rsv * snv.x, 0.f);
        o.y = fmaxf(a.y + bv.y - rsv * snv.y, 0.f);
        o.z = fmaxf(a.z + bv.z - rsv * snv.z, 0.f);
        o.w = fmaxf(a.w + bv.w - rsv * snv.w, 0.f);
        *(float4*)&sh[row][cq] = o;
    }
    __syncthreads();
    int h = t & 127, rg = t >> 7;        // waves 0,1 -> rows 0..7; waves 2,3 -> rows 8..15
    float acc[8] = {};
    for (int n = 0; n < 256; ++n) {
        float wv = Wq1[(size_t)n * QH + h];
#pragma unroll
        for (int r = 0; r < 8; ++r) acc[r] = fmaf(sh[rg * 8 + r][n], wv, acc[r]);
    }
    float b1v = bq1[h], w2v = Wq2[h];
    int wid = t >> 6, lane = t & 63;
#pragma unroll
    for (int r = 0; r < 8; ++r) {
        float v = fmaxf(acc[r] + b1v, 0.f) * w2v;
#pragma unroll
        for (int d = 32; d > 0; d >>= 1) v += __shfl_down(v, d, 64);
        if (lane == 0) red[wid][r] = v;
    }
    __syncthreads();
    if (t < 16) {
        int rg2 = t >> 3, r = t & 7;
        out[m0 + rg2 * 8 + r] = red[rg2 * 2][r] + red[rg2 * 2 + 1][r] + bq2[0];
    }
}

extern "C" void kernel_launch(void* const* d_in, const int* in_sizes, int n_in,
                              void* d_out, int out_size, void* d_ws, size_t ws_size,
                              hipStream_t stream) {
    const float* state = (const float*)d_in[0];
    const float* adj   = (const float*)d_in[1];
    const float* gamma = (const float*)d_in[2];
    const float* beta  = (const float*)d_in[3];
    const float* W1    = (const float*)d_in[4];
    const float* b1    = (const float*)d_in[5];
    const float* W2    = (const float*)d_in[6];
    const float* b2    = (const float*)d_in[7];
    const float* Wq1   = (const float*)d_in[8];
    const float* bq1   = (const float*)d_in[9];
    const float* Wq2   = (const float*)d_in[10];
    const float* bq2   = (const float*)d_in[11];
    float* out = (float*)d_out;

    char* ws = (char*)d_ws;
    float* psum  = (float*)(ws + 0);         // 128KB
    float* psq   = (float*)(ws + 131072);    // 128KB
    float* scale = (float*)(ws + 262144);
    float* shift = (float*)(ws + 262656);
    float* c1    = (float*)(ws + 263168);
    float* colA  = (float*)(ws + 264192);    // colsum(Y1q)
    float* colB  = (float*)(ws + 265216);    // colsum(Y2q)
    float* colH1 = (float*)(ws + 266240);    // colsum(H1 fp32)
    float* s2    = (float*)(ws + 267264);
    unsigned short* W1st = (unsigned short*)(ws + 268288);   // [256][128] bf16
    unsigned short* W2t  = (unsigned short*)(ws + 333824);   // [256][256] bf16
    unsigned short* Ybuf = (unsigned short*)(ws + (size_t)1  * (1u << 20)); // [8192][256] bf16
    unsigned short* Ytb  = (unsigned short*)(ws + (size_t)5  * (1u << 20)); // [256][8192] bf16
    unsigned short* Hbuf = (unsigned short*)(ws + (size_t)9  * (1u << 20)); // [8192][256] bf16
    float*          rsA  = (float*)(ws + (size_t)14 * (1u << 20));          // [8192] fp32
    float*          Cp   = (float*)(ws + (size_t)22 * (1u << 20));          // [8][8192][256] fp32 (64MB)
    unsigned short* Abf  = (unsigned short*)(ws + (size_t)128 * (1u << 20)); // [8192][8192] bf16 (134MB)

    k_castA<<<8192, 256, 0, stream>>>(adj, Abf, rsA);
    k_zero<<<4, 256, 0, stream>>>(colA);     // colA..s2 contiguous 4KB
    k_stats<<<256, 128, 0, stream>>>(state, psum, psq);
    k_finalize<<<1, 256, 0, stream>>>(psum, psq, gamma, beta, W1, scale, shift, c1);
    k_prep_weights<<<384, 256, 0, stream>>>(W1, W2, scale, W1st, W2t);

    // Y1 = bn(state) @ W1  (= state @ (scale*W1) + c1); colsum(Y1_true) == 0 exactly
    k_small_gemm<256, 128, true, true><<<256, 256, 0, stream>>>(state, W1st, c1, Ybuf);
    k_transpose<<<dim3(128, 4), 256, 0, stream>>>(Ybuf, Ytb, colA);
    k_big_gemm2<<<dim3(64, 8), 512, 0, stream>>>(Abf, Ytb, Cp);
    k_reduce8<<<512, 256, 0, stream>>>(Cp, rsA, b1, colA, Hbuf, colH1);   // H1 bf16 + colsum

    // Y2 = H1 @ W2; colsum(Y2_true) = colH1 @ W2 (fp32)
    k_small_gemm<256, 256, false, false><<<256, 256, 0, stream>>>(Hbuf, W2t, nullptr, Ybuf);
    k_transpose<<<dim3(128, 4), 256, 0, stream>>>(Ybuf, Ytb, colB);
    k_s2<<<1, 256, 0, stream>>>(colB, colH1, W2, s2);
    k_big_gemm2<<<dim3(64, 8), 512, 0, stream>>>(Abf, Ytb, Cp);
    k_reduce_qhead<<<512, 256, 0, stream>>>(Cp, rsA, b2, s2, Wq1, bq1, Wq2, bq2, out);
}